// Round 1
// baseline (193.724 us; speedup 1.0000x reference)
//
#include <hip/hip_runtime.h>
#include <stdint.h>

#define N_NODES 8192
#define N_FEAT  512
#define EMB     128
#define N_HEADS 4
#define TILE    64
#define TGRID   (N_NODES / TILE)   // 128

typedef __attribute__((ext_vector_type(8))) short bf16x8;
typedef __attribute__((ext_vector_type(4))) float f32x4;

__device__ __forceinline__ unsigned short f2bf(float f) {
  union { float f; unsigned int u; } x; x.f = f;
  unsigned int r = (x.u + 0x7FFFu + ((x.u >> 16) & 1u)) >> 16;
  return (unsigned short)r;
}

// ---------- kernel 1: X_emb = X @ W (f32), 8 rows per block ----------
__global__ void __launch_bounds__(256) xw_kernel(const float* __restrict__ X,
                                                 const float* __restrict__ W,
                                                 float* __restrict__ Xe) {
  __shared__ float xs[8][N_FEAT];   // 16 KB
  const int t = threadIdx.x;
  const int row0 = blockIdx.x * 8;
#pragma unroll
  for (int i = 0; i < 16; ++i) {
    int idx = t + i * 256;
    xs[idx >> 9][idx & 511] = X[(size_t)(row0 + (idx >> 9)) * N_FEAT + (idx & 511)];
  }
  __syncthreads();
  const int j = t & 127;
  const int rh = t >> 7;           // 0/1 -> rows rh*4 .. rh*4+3
  float a0 = 0.f, a1 = 0.f, a2 = 0.f, a3 = 0.f;
  for (int k = 0; k < N_FEAT; k += 4) {
    float w0 = W[(k + 0) * EMB + j];
    float w1 = W[(k + 1) * EMB + j];
    float w2 = W[(k + 2) * EMB + j];
    float w3 = W[(k + 3) * EMB + j];
#pragma unroll
    for (int u = 0; u < 4; ++u) {
      float w = (u == 0) ? w0 : (u == 1) ? w1 : (u == 2) ? w2 : w3;
      a0 += xs[rh * 4 + 0][k + u] * w;
      a1 += xs[rh * 4 + 1][k + u] * w;
      a2 += xs[rh * 4 + 2][k + u] * w;
      a3 += xs[rh * 4 + 3][k + u] * w;
    }
  }
  Xe[(size_t)(row0 + rh * 4 + 0) * EMB + j] = a0;
  Xe[(size_t)(row0 + rh * 4 + 1) * EMB + j] = a1;
  Xe[(size_t)(row0 + rh * 4 + 2) * EMB + j] = a2;
  Xe[(size_t)(row0 + rh * 4 + 3) * EMB + j] = a3;
}

// ---------- kernel 2: row-normalize (/(||row||+eps)) + cast to bf16 ----------
// one wave per 128-elem row, 4 rows per block
__global__ void __launch_bounds__(256) norm_kernel(const float* __restrict__ in,
                                                   unsigned short* __restrict__ out,
                                                   int nrows) {
  const int row = blockIdx.x * 4 + (threadIdx.x >> 6);
  const int lane = threadIdx.x & 63;
  if (row >= nrows) return;
  float2 v = *(const float2*)&in[(size_t)row * EMB + lane * 2];
  float ss = v.x * v.x + v.y * v.y;
#pragma unroll
  for (int off = 32; off; off >>= 1) ss += __shfl_xor(ss, off);
  const float s = 1.0f / (sqrtf(ss) + 1e-6f);
  union { unsigned short u[2]; unsigned int w; } o;
  o.u[0] = f2bf(v.x * s);
  o.u[1] = f2bf(v.y * s);
  *(unsigned int*)&out[(size_t)row * EMB + lane * 2] = o.w;
}

// ---------- kernel 3: fused affinity / head-max / symmetrize / scale / pow ----------
// stage a 64x128 bf16 tile into LDS with XOR-swizzle (chunk ^= row&7)
__device__ __forceinline__ void stage_tile(unsigned short* dst,
                                           const unsigned short* __restrict__ src,
                                           int t) {
#pragma unroll
  for (int i = 0; i < 4; ++i) {
    int ch = t + i * 256;            // 0..1023 16B-chunks
    int row = ch >> 4;               // 0..63
    int kc = ch & 15;                // 0..15 (16B chunk within row)
    uint4 v = *(const uint4*)&src[row * EMB + kc * 8];
    *(uint4*)&dst[row * EMB + ((kc ^ (row & 7)) << 3)] = v;
  }
}

// read one 16x32 MFMA fragment (A or B operand) from a swizzled tile
__device__ __forceinline__ bf16x8 ldfrag(const unsigned short* tile, int rowbase,
                                         int kk, int lane) {
  int r = rowbase + (lane & 15);
  int kc = kk * 4 + (lane >> 4);     // original 16B chunk index
  return *(const bf16x8*)&tile[r * EMB + ((kc ^ (r & 7)) << 3)];
}

__global__ void __launch_bounds__(256) affinity_kernel(const unsigned short* __restrict__ Xen,
                                                       const unsigned short* __restrict__ Zn,
                                                       const float* __restrict__ betap,
                                                       float* __restrict__ out) {
  __shared__ unsigned short XA[TILE * EMB];   // 16 KB, Xe rows of bi
  __shared__ unsigned short XB[TILE * EMB];   // 16 KB, Xe rows of bj
  __shared__ unsigned short ZT[TILE * 65 * 2];// 16.64 KB: Z stage, later float Tbuf[64][65]
  float (*Tbuf)[65] = (float(*)[65])ZT;

  // triangular block decode: p -> (bi <= bj)
  int p = blockIdx.x;
  int i = (int)(((float)(2 * TGRID + 1) -
                 sqrtf((float)((2 * TGRID + 1) * (2 * TGRID + 1) - 8 * p))) * 0.5f);
  if (i < 0) i = 0;
  if (i > TGRID - 1) i = TGRID - 1;
  while (i > 0 && i * TGRID - i * (i - 1) / 2 > p) --i;
  while ((i + 1) * TGRID - (i + 1) * i / 2 <= p) ++i;
  const int bi = i;
  const int bj = i + (p - (i * TGRID - i * (i - 1) / 2));
  const bool diag = (bi == bj);

  const int t = threadIdx.x;
  const int lane = t & 63;
  const int wid = t >> 6;       // 4 waves, 2x2 grid; each wave owns 32x32
  const int wr = (wid >> 1) * 32;
  const int wc = (wid & 1) * 32;

  stage_tile(XA, Xen + (size_t)bi * TILE * EMB, t);
  stage_tile(XB, Xen + (size_t)bj * TILE * EMB, t);

  f32x4 maxI[2][2], maxJ[2][2];
#pragma unroll
  for (int mi = 0; mi < 2; ++mi)
#pragma unroll
    for (int nj = 0; nj < 2; ++nj)
#pragma unroll
      for (int q = 0; q < 4; ++q) { maxI[mi][nj][q] = -3.0e38f; maxJ[mi][nj][q] = -3.0e38f; }

  for (int h = 0; h < N_HEADS; ++h) {
    // ---- A_ij = Z[h][bi-rows] @ Xe[bj-rows]^T ----
    __syncthreads();   // previous consumers of ZT done
    stage_tile(ZT, Zn + ((size_t)h * N_NODES + (size_t)bi * TILE) * EMB, t);
    __syncthreads();
    {
      f32x4 acc[2][2] = {};
#pragma unroll
      for (int kk = 0; kk < 4; ++kk) {
        bf16x8 za0 = ldfrag(ZT, wr + 0, kk, lane);
        bf16x8 za1 = ldfrag(ZT, wr + 16, kk, lane);
        bf16x8 xb0 = ldfrag(XB, wc + 0, kk, lane);
        bf16x8 xb1 = ldfrag(XB, wc + 16, kk, lane);
        acc[0][0] = __builtin_amdgcn_mfma_f32_16x16x32_bf16(za0, xb0, acc[0][0], 0, 0, 0);
        acc[0][1] = __builtin_amdgcn_mfma_f32_16x16x32_bf16(za0, xb1, acc[0][1], 0, 0, 0);
        acc[1][0] = __builtin_amdgcn_mfma_f32_16x16x32_bf16(za1, xb0, acc[1][0], 0, 0, 0);
        acc[1][1] = __builtin_amdgcn_mfma_f32_16x16x32_bf16(za1, xb1, acc[1][1], 0, 0, 0);
      }
#pragma unroll
      for (int mi = 0; mi < 2; ++mi)
#pragma unroll
        for (int nj = 0; nj < 2; ++nj)
#pragma unroll
          for (int q = 0; q < 4; ++q)
            maxI[mi][nj][q] = fmaxf(maxI[mi][nj][q], acc[mi][nj][q]);
    }
    if (!diag) {
      // ---- A_ji = Z[h][bj-rows] @ Xe[bi-rows]^T ----
      __syncthreads();
      stage_tile(ZT, Zn + ((size_t)h * N_NODES + (size_t)bj * TILE) * EMB, t);
      __syncthreads();
      f32x4 acc[2][2] = {};
#pragma unroll
      for (int kk = 0; kk < 4; ++kk) {
        bf16x8 za0 = ldfrag(ZT, wr + 0, kk, lane);
        bf16x8 za1 = ldfrag(ZT, wr + 16, kk, lane);
        bf16x8 xa0 = ldfrag(XA, wc + 0, kk, lane);
        bf16x8 xa1 = ldfrag(XA, wc + 16, kk, lane);
        acc[0][0] = __builtin_amdgcn_mfma_f32_16x16x32_bf16(za0, xa0, acc[0][0], 0, 0, 0);
        acc[0][1] = __builtin_amdgcn_mfma_f32_16x16x32_bf16(za0, xa1, acc[0][1], 0, 0, 0);
        acc[1][0] = __builtin_amdgcn_mfma_f32_16x16x32_bf16(za1, xa0, acc[1][0], 0, 0, 0);
        acc[1][1] = __builtin_amdgcn_mfma_f32_16x16x32_bf16(za1, xa1, acc[1][1], 0, 0, 0);
      }
#pragma unroll
      for (int mi = 0; mi < 2; ++mi)
#pragma unroll
        for (int nj = 0; nj < 2; ++nj)
#pragma unroll
          for (int q = 0; q < 4; ++q)
            maxJ[mi][nj][q] = fmaxf(maxJ[mi][nj][q], acc[mi][nj][q]);
    }
  }

  // ---- epilogue: symmetrize via LDS transpose, scale, pow, write both tiles ----
  __syncthreads();  // done reading ZT as bf16 stage; reuse as Tbuf
  // phase A: write the "other" tile (A_ji, or A_ii for diag) at its natural (r,c)
#pragma unroll
  for (int mi = 0; mi < 2; ++mi)
#pragma unroll
    for (int nj = 0; nj < 2; ++nj)
#pragma unroll
      for (int q = 0; q < 4; ++q) {
        int r = wr + mi * 16 + (lane >> 4) * 4 + q;
        int c = wc + nj * 16 + (lane & 15);
        Tbuf[r][c] = diag ? maxI[mi][nj][q] : maxJ[mi][nj][q];
      }
  __syncthreads();

  const float beta = betap[0];
  const bool beta1 = (beta == 1.0f);
  float vv[2][2][4];
#pragma unroll
  for (int mi = 0; mi < 2; ++mi)
#pragma unroll
    for (int nj = 0; nj < 2; ++nj)
#pragma unroll
      for (int q = 0; q < 4; ++q) {
        int r = wr + mi * 16 + (lane >> 4) * 4 + q;
        int c = wc + nj * 16 + (lane & 15);
        float a = maxI[mi][nj][q];
        float b = Tbuf[c][r];                // A[j][i]
        float v = 0.25f * (a + b) + 0.5f;    // ((a+b)/2 + 1)/2
        if (!beta1) v = powf(v, beta);
        out[(size_t)(bi * TILE + r) * N_NODES + (size_t)(bj * TILE + c)] = v;
        vv[mi][nj][q] = v;
      }

  if (!diag) {
    __syncthreads();
    // phase C: transposed store of result into Tbuf -> Tbuf[row][col] = lower tile
#pragma unroll
    for (int mi = 0; mi < 2; ++mi)
#pragma unroll
      for (int nj = 0; nj < 2; ++nj)
#pragma unroll
        for (int q = 0; q < 4; ++q) {
          int r = wr + mi * 16 + (lane >> 4) * 4 + q;
          int c = wc + nj * 16 + (lane & 15);
          Tbuf[c][r] = vv[mi][nj][q];
        }
    __syncthreads();
    // phase D: coalesced write of the mirrored tile
#pragma unroll
    for (int i2 = 0; i2 < 16; ++i2) {
      int row = (t >> 6) + i2 * 4;
      int col = t & 63;
      out[(size_t)(bj * TILE + row) * N_NODES + (size_t)(bi * TILE + col)] = Tbuf[row][col];
    }
  }
}

extern "C" void kernel_launch(void* const* d_in, const int* in_sizes, int n_in,
                              void* d_out, int out_size, void* d_ws, size_t ws_size,
                              hipStream_t stream) {
  const float* X = (const float*)d_in[0];
  const float* W = (const float*)d_in[1];
  const float* Z = (const float*)d_in[2];
  const float* beta = (const float*)d_in[3];
  float* out = (float*)d_out;
  char* ws = (char*)d_ws;

  float* Xe = (float*)ws;                                    // 4 MiB f32 [8192][128]
  unsigned short* Xen = (unsigned short*)(ws + (4u << 20));  // 2 MiB bf16 normalized
  unsigned short* Zn  = (unsigned short*)(ws + (6u << 20));  // 8 MiB bf16 normalized

  hipLaunchKernelGGL(xw_kernel, dim3(N_NODES / 8), dim3(256), 0, stream, X, W, Xe);
  hipLaunchKernelGGL(norm_kernel, dim3(N_NODES / 4), dim3(256), 0, stream, Xe, Xen, N_NODES);
  hipLaunchKernelGGL(norm_kernel, dim3(N_HEADS * N_NODES / 4), dim3(256), 0, stream,
                     Z, Zn, N_HEADS * N_NODES);
  hipLaunchKernelGGL(affinity_kernel, dim3(TGRID * (TGRID + 1) / 2), dim3(256), 0, stream,
                     Xen, Zn, beta, out);
}

// Round 3
// 182.979 us; speedup vs baseline: 1.0587x; 1.0587x over previous
//
#include <hip/hip_runtime.h>
#include <stdint.h>
#include <stddef.h>

#define N_NODES 8192
#define N_FEAT  512
#define EMB     128
#define N_HEADS 4
#define TILE    128
#define TG      (N_NODES / TILE)        // 64
#define NPAIR   (TG * (TG + 1) / 2)     // 2080
#define TILE_ELEMS (TILE * EMB)         // 16384 shorts = 32KB

typedef __attribute__((ext_vector_type(8)))  short bf16x8;
typedef __attribute__((ext_vector_type(16))) float f32x16;

__device__ __forceinline__ unsigned short f2bf(float f) {
  union { float f; unsigned int u; } x; x.f = f;
  unsigned int r = (x.u + 0x7FFFu + ((x.u >> 16) & 1u)) >> 16;
  return (unsigned short)r;
}
__device__ __forceinline__ float bf2f(unsigned short u) {
  union { unsigned int u; float f; } x; x.u = ((unsigned int)u) << 16;
  return x.f;
}

// async global->LDS, 16B per lane. LDS dest must be wave-uniform base (HW adds lane*16).
__device__ __forceinline__ void gl_lds16(const unsigned short* g, unsigned short* l) {
  __builtin_amdgcn_global_load_lds(
      (__attribute__((address_space(1))) void*)(void*)g,
      (__attribute__((address_space(3))) void*)l, 16, 0, 0);
}

// swizzled-tile element offset (in shorts) for (row r in [0,128), col c in [0,128))
__device__ __forceinline__ int swz_off(int r, int c) {
  int kc = c >> 3;
  return r * EMB + (((kc ^ (r & 7)) << 3) | (c & 7));
}

// Tbuf (bf16 [128][128]) XOR-swizzled index, conflict-free both orientations
__device__ __forceinline__ int tidx(int r, int c) {
  int m = (r & 31) ^ ((r & 4) << 2);
  return r * 128 + (c ^ m);
}

// ---------- kernel 1: X_emb = X@W, row-normalize, cast bf16, swizzled-tile write ----------
__global__ void __launch_bounds__(512) xw_kernel(const float* __restrict__ X,
                                                 const float* __restrict__ W,
                                                 unsigned short* __restrict__ Xen) {
  __shared__ float xs[32][N_FEAT];    // 64KB
  const int t = threadIdx.x;
  const int row0 = blockIdx.x * 32;
#pragma unroll
  for (int i = 0; i < 8; ++i) {
    int e4 = i * 512 + t;             // float4 index, 4096 total
    int row = e4 >> 7;                // 128 float4 per row
    int col = (e4 & 127) * 4;
    *(float4*)&xs[row][col] = *(const float4*)&X[(size_t)(row0 + row) * N_FEAT + col];
  }
  __syncthreads();
  const int c0 = (t & 31) * 4;
  const int r0 = (t >> 5) * 2;
  float a00=0.f,a01=0.f,a02=0.f,a03=0.f,a10=0.f,a11=0.f,a12=0.f,a13=0.f;
  for (int k = 0; k < N_FEAT; k += 2) {
    float4 w0 = *(const float4*)&W[(size_t)k * EMB + c0];
    float4 w1 = *(const float4*)&W[(size_t)(k + 1) * EMB + c0];
    float x00 = xs[r0][k],     x01 = xs[r0][k + 1];
    float x10 = xs[r0 + 1][k], x11 = xs[r0 + 1][k + 1];
    a00 += x00*w0.x; a01 += x00*w0.y; a02 += x00*w0.z; a03 += x00*w0.w;
    a10 += x10*w0.x; a11 += x10*w0.y; a12 += x10*w0.z; a13 += x10*w0.w;
    a00 += x01*w1.x; a01 += x01*w1.y; a02 += x01*w1.z; a03 += x01*w1.w;
    a10 += x11*w1.x; a11 += x11*w1.y; a12 += x11*w1.z; a13 += x11*w1.w;
  }
  float s0 = a00*a00 + a01*a01 + a02*a02 + a03*a03;
  float s1 = a10*a10 + a11*a11 + a12*a12 + a13*a13;
#pragma unroll
  for (int off = 16; off >= 1; off >>= 1) {
    s0 += __shfl_xor(s0, off);
    s1 += __shfl_xor(s1, off);
  }
  float inv0 = 1.0f / (sqrtf(s0) + 1e-6f);
  float inv1 = 1.0f / (sqrtf(s1) + 1e-6f);
  // swizzled bf16 write: rows n0=row0+r0, n1=n0+1; 4 cols at c0 (c0&7 in {0,4} -> 8B aligned)
  union { unsigned short u[4]; uint2 v; } o0, o1;
  o0.u[0]=f2bf(a00*inv0); o0.u[1]=f2bf(a01*inv0); o0.u[2]=f2bf(a02*inv0); o0.u[3]=f2bf(a03*inv0);
  o1.u[0]=f2bf(a10*inv1); o1.u[1]=f2bf(a11*inv1); o1.u[2]=f2bf(a12*inv1); o1.u[3]=f2bf(a13*inv1);
  int n0 = row0 + r0;
  int t0 = n0 >> 7, rr0 = n0 & 127;
  int t1 = (n0 + 1) >> 7, rr1 = (n0 + 1) & 127;
  *(uint2*)&Xen[(size_t)t0 * TILE_ELEMS + swz_off(rr0, c0)] = o0.v;
  *(uint2*)&Xen[(size_t)t1 * TILE_ELEMS + swz_off(rr1, c0)] = o1.v;
}

// ---------- kernel 2: Z row-normalize + bf16 + swizzled-tile write ----------
__global__ void __launch_bounds__(256) znorm_kernel(const float* __restrict__ in,
                                                    unsigned short* __restrict__ out) {
  const int row = blockIdx.x * 4 + (threadIdx.x >> 6);
  const int lane = threadIdx.x & 63;
  float2 v = *(const float2*)&in[(size_t)row * EMB + lane * 2];
  float ss = v.x * v.x + v.y * v.y;
#pragma unroll
  for (int off = 32; off >= 1; off >>= 1) ss += __shfl_xor(ss, off);
  const float s = 1.0f / (sqrtf(ss) + 1e-6f);
  union { unsigned short u[2]; unsigned int w; } o;
  o.u[0] = f2bf(v.x * s);
  o.u[1] = f2bf(v.y * s);
  int tile = row >> 7, r = row & 127, c = lane * 2;
  *(unsigned int*)&out[(size_t)tile * TILE_ELEMS + swz_off(r, c)] = o.w;
}

// ---------- kernel 3: fused affinity ----------
__device__ __forceinline__ void stageZ(unsigned short* dstLds, const unsigned short* src,
                                       int wid, int lane) {
#pragma unroll
  for (int i = 0; i < 4; ++i) {
    int cbase = i * 512 + wid * 64;          // 16B-chunk base, wave-uniform
    gl_lds16(src + (size_t)(cbase + lane) * 8, dstLds + (size_t)cbase * 8);
  }
}

__device__ __forceinline__ void do_stage(const unsigned short* cur, const bf16x8 (&XB)[8],
                                         f32x16 (&M)[2], int R0, int fr, int fh) {
  f32x16 acc0 = {}, acc1 = {};
  const int rb = R0 + fr;
  const int sw = rb & 7;
  const unsigned short* base0 = cur + rb * EMB;
#pragma unroll
  for (int kk = 0; kk < 8; ++kk) {
    int kc = kk * 2 + fh;
    int off = ((kc ^ sw) << 3);
    bf16x8 a0 = *(const bf16x8*)(base0 + off);
    bf16x8 a1 = *(const bf16x8*)(base0 + 32 * EMB + off);
    acc0 = __builtin_amdgcn_mfma_f32_32x32x16_bf16(a0, XB[kk], acc0, 0, 0, 0);
    acc1 = __builtin_amdgcn_mfma_f32_32x32x16_bf16(a1, XB[kk], acc1, 0, 0, 0);
  }
#pragma unroll
  for (int q = 0; q < 16; ++q) {
    M[0][q] = fmaxf(M[0][q], acc0[q]);
    M[1][q] = fmaxf(M[1][q], acc1[q]);
  }
}

__global__ void __launch_bounds__(512, 1) affinity_kernel(const unsigned short* __restrict__ Xen,
                                                          const unsigned short* __restrict__ Zn,
                                                          const float* __restrict__ betap,
                                                          float* __restrict__ out) {
  __shared__ __align__(16) unsigned short Zb[2][TILE_ELEMS];  // 64KB double buffer
  unsigned short* Tb = &Zb[0][0];                             // bf16 [128][128] overlay (post-compute)

  // XCD-bijective swizzle (2080 % 8 == 0)
  int bid = blockIdx.x;
  int p = (bid & 7) * (NPAIR / 8) + (bid >> 3);
  // triangular decode p -> (bi <= bj)
  int i = (int)(((float)(2 * TG + 1) -
                 sqrtf((float)((2 * TG + 1) * (2 * TG + 1) - 8 * p))) * 0.5f);
  if (i < 0) i = 0;
  if (i > TG - 1) i = TG - 1;
  while (i > 0 && i * TG - i * (i - 1) / 2 > p) --i;
  while ((i + 1) * TG - (i + 1) * i / 2 <= p) ++i;
  const int bi = i;
  const int bj = i + (p - (i * TG - i * (i - 1) / 2));
  const bool diag = (bi == bj);
  const int NS = diag ? 4 : 8;

  const int t = threadIdx.x;
  const int lane = t & 63;
  const int wid = t >> 6;
  const int R0 = (wid >> 2) * 64;   // wave rows within tile
  const int C0 = (wid & 3) * 32;    // wave cols within tile
  const int fr = lane & 31;
  const int fh = lane >> 5;

  // kick off Z stage 0 (head 0, bi tile)
  stageZ(Zb[0], Zn + ((size_t)(0 * TG + bi) << 14), wid, lane);

  // X B-fragments -> registers (col = fr, k-half = fh), from swizzled global tiles
  bf16x8 XjB[8], XiB[8];
  {
    const unsigned short* xj = Xen + ((size_t)bj << 14);
    const int r = C0 + fr;
    const int sw = r & 7;
#pragma unroll
    for (int kk = 0; kk < 8; ++kk) {
      int kc = kk * 2 + fh;
      XjB[kk] = *(const bf16x8*)&xj[r * EMB + ((kc ^ sw) << 3)];
    }
    if (!diag) {
      const unsigned short* xi = Xen + ((size_t)bi << 14);
#pragma unroll
      for (int kk = 0; kk < 8; ++kk) {
        int kc = kk * 2 + fh;
        XiB[kk] = *(const bf16x8*)&xi[r * EMB + ((kc ^ sw) << 3)];
      }
    }
  }

  f32x16 maxI[2], maxJ[2];
#pragma unroll
  for (int q = 0; q < 16; ++q) {
    maxI[0][q] = -3.0e38f; maxI[1][q] = -3.0e38f;
    maxJ[0][q] = -3.0e38f; maxJ[1][q] = -3.0e38f;
  }

  __syncthreads();   // stage 0 ready (vmcnt drained by barrier)

  // stages 0..3: Pij = Z[h][bi-rows] @ Xj^T  -> maxI
#pragma unroll
  for (int s = 0; s < 4; ++s) {
    if (s + 1 < NS) {
      int h = (s + 1) & 3;
      int tl = (s + 1 < 4) ? bi : bj;
      stageZ(Zb[(s + 1) & 1], Zn + ((size_t)(h * TG + tl) << 14), wid, lane);
    }
    do_stage(Zb[s & 1], XjB, maxI, R0, fr, fh);
    __syncthreads();
  }
  // stages 4..7: Pji = Z[h][bj-rows] @ Xi^T  -> maxJ
  if (!diag) {
#pragma unroll
    for (int s = 4; s < 8; ++s) {
      if (s < 7) {
        int h = (s + 1) & 3;
        stageZ(Zb[(s + 1) & 1], Zn + ((size_t)(h * TG + bj) << 14), wid, lane);
      }
      do_stage(Zb[s & 1], XiB, maxJ, R0, fr, fh);
      __syncthreads();
    }
  }

  // ---- epilogue ----
  // P1: Tb[tidx(r,c)] = Pji (or Pii for diag), natural orientation, bf16
#pragma unroll
  for (int ma = 0; ma < 2; ++ma)
#pragma unroll
    for (int q = 0; q < 16; ++q) {
      int r = R0 + ma * 32 + (q & 3) + 8 * (q >> 2) + 4 * fh;
      int c = C0 + fr;
      Tb[tidx(r, c)] = f2bf(diag ? maxI[ma][q] : maxJ[ma][q]);
    }
  __syncthreads();

  const float beta = betap[0];
  const bool bp = (beta != 1.0f);
  float vv[2][16];
#pragma unroll
  for (int ma = 0; ma < 2; ++ma)
#pragma unroll
    for (int q = 0; q < 16; ++q) {
      int r = R0 + ma * 32 + (q & 3) + 8 * (q >> 2) + 4 * fh;
      int c = C0 + fr;
      float a = maxI[ma][q];
      float b = bf2f(Tb[tidx(c, r)]);      // Pji^T at (r,c)
      float v = 0.25f * (a + b) + 0.5f;    // ((a+b)/2 + 1)/2
      if (bp) v = powf(v, beta);
      out[(size_t)(bi * TILE + r) * N_NODES + (size_t)(bj * TILE + c)] = v;
      vv[ma][q] = v;
    }

  if (!diag) {
    __syncthreads();
    // P3: store result transposed (lower tile natural orientation)
#pragma unroll
    for (int ma = 0; ma < 2; ++ma)
#pragma unroll
      for (int q = 0; q < 16; ++q) {
        int r = R0 + ma * 32 + (q & 3) + 8 * (q >> 2) + 4 * fh;
        int c = C0 + fr;
        Tb[tidx(c, r)] = f2bf(vv[ma][q]);
      }
    __syncthreads();
    // P4: coalesced write of mirrored tile
#pragma unroll
    for (int it = 0; it < 32; ++it) {
      int row = it * 4 + (t >> 7);
      int col = t & 127;
      out[(size_t)(bj * TILE + row) * N_NODES + (size_t)(bi * TILE + col)] =
          bf2f(Tb[tidx(row, col)]);
    }
  }
}

extern "C" void kernel_launch(void* const* d_in, const int* in_sizes, int n_in,
                              void* d_out, int out_size, void* d_ws, size_t ws_size,
                              hipStream_t stream) {
  const float* X = (const float*)d_in[0];
  const float* W = (const float*)d_in[1];
  const float* Z = (const float*)d_in[2];
  const float* beta = (const float*)d_in[3];
  float* out = (float*)d_out;
  char* ws = (char*)d_ws;

  unsigned short* Xen = (unsigned short*)ws;                // 2 MiB swizzled bf16 tiles
  unsigned short* Zn  = (unsigned short*)(ws + (2u << 20)); // 8 MiB swizzled bf16 tiles

  hipLaunchKernelGGL(xw_kernel, dim3(N_NODES / 32), dim3(512), 0, stream, X, W, Xen);
  hipLaunchKernelGGL(znorm_kernel, dim3(N_HEADS * N_NODES / 4), dim3(256), 0, stream, Z, Zn);
  hipLaunchKernelGGL(affinity_kernel, dim3(NPAIR), dim3(512), 0, stream, Xen, Zn, beta, out);
}